// Round 1
// baseline (72027.094 us; speedup 1.0000x reference)
//
#include <hip/hip_runtime.h>
#include <math.h>

#define BS   128
#define LAT  512
#define HID  1024

__device__ __forceinline__ float sigm(float x) { return 1.0f / (1.0f + expf(-x)); }

// ---------------------------------------------------------------------------
// K1: gates kernel. For one direction d and tile (m0, u0):
//   z[b, g*HID+u] = sum_k x[b,k] Wih[g*HID+u, k] + sum_k h[b,k] Whh[g*HID+u, k] + bias
// then LSTM gates -> hnew, c (in-place c, owner-computes so race-free).
// Tile: M=64 batches x N=64 z-cols (16 units x 4 gates). 256 thr, micro 4x4.
// Grid: 2 dirs x 2 Mtiles x 64 utiles = 256 blocks.
// ---------------------------------------------------------------------------
__global__ __launch_bounds__(256) void k_gates(
    const float* __restrict__ x,
    const float* __restrict__ hprev_f, float* __restrict__ hnew_f, float* __restrict__ c_f,
    const float* __restrict__ Wih_f, const float* __restrict__ Whh_f, const float* __restrict__ b_f,
    const float* __restrict__ hprev_b, float* __restrict__ hnew_b, float* __restrict__ c_b,
    const float* __restrict__ Wih_b, const float* __restrict__ Whh_b, const float* __restrict__ b_b)
{
    const int bid = blockIdx.x;
    const int dir = bid >> 7;          // 0..1
    const int rem = bid & 127;
    const int m0 = (rem >> 6) * 64;    // batch tile
    const int u0 = (rem & 63) * 16;    // hidden-unit tile

    const float* hprev = dir ? hprev_b : hprev_f;
    float* hnew        = dir ? hnew_b  : hnew_f;
    float* cst         = dir ? c_b     : c_f;
    const float* Wih   = dir ? Wih_b   : Wih_f;
    const float* Whh   = dir ? Whh_b   : Whh_f;
    const float* bias  = dir ? b_b     : b_f;

    __shared__ float sA[64 * 36];   // stride 36 floats: 16B-aligned rows, 2-way banks (free)
    __shared__ float sW[64 * 36];

    const int tid = threadIdx.x;
    const int tr = tid & 15;        // row group
    const int tc = tid >> 4;        // col group (= unit within tile)

    float acc[4][4];
#pragma unroll
    for (int i = 0; i < 4; ++i)
#pragma unroll
        for (int j = 0; j < 4; ++j) acc[i][j] = 0.0f;

    for (int phase = 0; phase < 2; ++phase) {
        const float* A = phase ? hprev : x;
        const float* W = phase ? Whh : Wih;
        const int kw = phase ? HID : LAT;   // row stride of A and W

        for (int k0 = 0; k0 < kw; k0 += 32) {
            // load A tile (64 x 32) and W tile (64 z-cols x 32), float4 coalesced
#pragma unroll
            for (int p = 0; p < 2; ++p) {
                const int idx = p * 256 + tid;       // 0..511
                const int row = idx >> 3;            // 0..63
                const int c4 = (idx & 7) * 4;        // 0,4,..,28
                const float4 av = *reinterpret_cast<const float4*>(
                    &A[(size_t)(m0 + row) * kw + k0 + c4]);
                *reinterpret_cast<float4*>(&sA[row * 36 + c4]) = av;
                // z-col "row": gate = row>>4, unit = u0 + (row&15)
                const int wr = (row >> 4) * HID + u0 + (row & 15);
                const float4 wv = *reinterpret_cast<const float4*>(
                    &W[(size_t)wr * kw + k0 + c4]);
                *reinterpret_cast<float4*>(&sW[row * 36 + c4]) = wv;
            }
            __syncthreads();

#pragma unroll
            for (int kk = 0; kk < 32; kk += 4) {
                float4 a4[4], w4[4];
#pragma unroll
                for (int i = 0; i < 4; ++i)
                    a4[i] = *reinterpret_cast<const float4*>(&sA[(tr + 16 * i) * 36 + kk]);
#pragma unroll
                for (int j = 0; j < 4; ++j)
                    w4[j] = *reinterpret_cast<const float4*>(&sW[(tc + 16 * j) * 36 + kk]);
#pragma unroll
                for (int i = 0; i < 4; ++i)
#pragma unroll
                    for (int j = 0; j < 4; ++j) {
                        acc[i][j] = fmaf(a4[i].x, w4[j].x, acc[i][j]);
                        acc[i][j] = fmaf(a4[i].y, w4[j].y, acc[i][j]);
                        acc[i][j] = fmaf(a4[i].z, w4[j].z, acc[i][j]);
                        acc[i][j] = fmaf(a4[i].w, w4[j].w, acc[i][j]);
                    }
            }
            __syncthreads();
        }
    }

    // epilogue: thread holds, per row, gates {i,f,g,o} of unit u0+tc (cols tc+16j)
    const int u = u0 + tc;
    const float bi = bias[u];
    const float bf = bias[HID + u];
    const float bg = bias[2 * HID + u];
    const float bo = bias[3 * HID + u];
#pragma unroll
    for (int i = 0; i < 4; ++i) {
        const int m = m0 + tr + 16 * i;
        const float zi = acc[i][0] + bi;
        const float zf = acc[i][1] + bf;
        const float zg = acc[i][2] + bg;
        const float zo = acc[i][3] + bo;
        const float cold = cst[(size_t)m * HID + u];
        const float c2 = sigm(zf) * cold + sigm(zi) * tanhf(zg);
        const float h2 = sigm(zo) * tanhf(c2);
        cst[(size_t)m * HID + u] = c2;
        hnew[(size_t)m * HID + u] = h2;
    }
}

// ---------------------------------------------------------------------------
// K2: x_next = hb @ W_out^T + b_out  (blocks 0..15, 64x64 tiles, K=1024)
//     out[b,t] = relu([hf|hb]) . W_fc1 + b_fc1  (blocks 16..143, one per batch)
// ---------------------------------------------------------------------------
__global__ __launch_bounds__(256) void k_next(
    const float* __restrict__ hf, const float* __restrict__ hb,
    const float* __restrict__ W_out, const float* __restrict__ b_out,
    const float* __restrict__ W_fc1, const float* __restrict__ b_fc1,
    float* __restrict__ x, float* __restrict__ out, int T, int t)
{
    const int bid = blockIdx.x;
    const int tid = threadIdx.x;

    if (bid < 16) {
        const int m0 = (bid >> 3) * 64;
        const int n0 = (bid & 7) * 64;
        __shared__ float sA[64 * 36];
        __shared__ float sW[64 * 36];
        const int tr = tid & 15;
        const int tc = tid >> 4;

        float acc[4][4];
#pragma unroll
        for (int i = 0; i < 4; ++i)
#pragma unroll
            for (int j = 0; j < 4; ++j) acc[i][j] = 0.0f;

        for (int k0 = 0; k0 < HID; k0 += 32) {
#pragma unroll
            for (int p = 0; p < 2; ++p) {
                const int idx = p * 256 + tid;
                const int row = idx >> 3;
                const int c4 = (idx & 7) * 4;
                const float4 av = *reinterpret_cast<const float4*>(
                    &hb[(size_t)(m0 + row) * HID + k0 + c4]);
                *reinterpret_cast<float4*>(&sA[row * 36 + c4]) = av;
                const float4 wv = *reinterpret_cast<const float4*>(
                    &W_out[(size_t)(n0 + row) * HID + k0 + c4]);
                *reinterpret_cast<float4*>(&sW[row * 36 + c4]) = wv;
            }
            __syncthreads();
#pragma unroll
            for (int kk = 0; kk < 32; kk += 4) {
                float4 a4[4], w4[4];
#pragma unroll
                for (int i = 0; i < 4; ++i)
                    a4[i] = *reinterpret_cast<const float4*>(&sA[(tr + 16 * i) * 36 + kk]);
#pragma unroll
                for (int j = 0; j < 4; ++j)
                    w4[j] = *reinterpret_cast<const float4*>(&sW[(tc + 16 * j) * 36 + kk]);
#pragma unroll
                for (int i = 0; i < 4; ++i)
#pragma unroll
                    for (int j = 0; j < 4; ++j) {
                        acc[i][j] = fmaf(a4[i].x, w4[j].x, acc[i][j]);
                        acc[i][j] = fmaf(a4[i].y, w4[j].y, acc[i][j]);
                        acc[i][j] = fmaf(a4[i].z, w4[j].z, acc[i][j]);
                        acc[i][j] = fmaf(a4[i].w, w4[j].w, acc[i][j]);
                    }
            }
            __syncthreads();
        }
#pragma unroll
        for (int i = 0; i < 4; ++i)
#pragma unroll
            for (int j = 0; j < 4; ++j) {
                const int m = m0 + tr + 16 * i;
                const int n = n0 + tc + 16 * j;
                x[(size_t)m * LAT + n] = acc[i][j] + b_out[n];
            }
    } else {
        const int b = bid - 16;      // batch index
        float s = 0.0f;
        for (int j = tid; j < 2 * HID; j += 256) {
            const float v = (j < HID) ? hf[(size_t)b * HID + j]
                                      : hb[(size_t)b * HID + (j - HID)];
            s += fmaxf(v, 0.0f) * W_fc1[j];
        }
        __shared__ float red[256];
        red[tid] = s;
        __syncthreads();
        for (int off = 128; off > 0; off >>= 1) {
            if (tid < off) red[tid] += red[tid + off];
            __syncthreads();
        }
        if (tid == 0) out[(size_t)b * T + t] = red[0] + b_fc1[0];
    }
}

// ---------------------------------------------------------------------------
// Host launcher.
// ws layout (floats): x(65536) | hf0 hb0 cf cb (4x131072, zeroed) | hf1 hb1
// ---------------------------------------------------------------------------
extern "C" void kernel_launch(void* const* d_in, const int* in_sizes, int n_in,
                              void* d_out, int out_size, void* d_ws, size_t ws_size,
                              hipStream_t stream) {
    const float* dec   = (const float*)d_in[0];
    // d_in[1] = lengths (unused: T derived from out_size)
    const float* Wih_f = (const float*)d_in[2];
    const float* Whh_f = (const float*)d_in[3];
    const float* b_f   = (const float*)d_in[4];
    const float* Wih_b = (const float*)d_in[5];
    const float* Whh_b = (const float*)d_in[6];
    const float* b_b   = (const float*)d_in[7];
    const float* W_out = (const float*)d_in[8];
    const float* b_out = (const float*)d_in[9];
    const float* W_fc1 = (const float*)d_in[10];
    const float* b_fc1 = (const float*)d_in[11];
    float* out = (float*)d_out;

    float* ws  = (float*)d_ws;
    float* xb  = ws;                       // 128*512
    float* hf0 = ws + 65536;
    float* hb0 = ws + 196608;
    float* cf  = ws + 327680;
    float* cb  = ws + 458752;
    float* hf1 = ws + 589824;
    float* hb1 = ws + 720896;
    float* hfp[2] = {hf0, hf1};
    float* hbp[2] = {hb0, hb1};

    // h0 = c0 = 0 (hf0,hb0,cf,cb are contiguous); x = decoder_input
    hipMemsetAsync(hf0, 0, (size_t)4 * 131072 * sizeof(float), stream);
    hipMemcpyAsync(xb, dec, (size_t)BS * LAT * sizeof(float),
                   hipMemcpyDeviceToDevice, stream);

    const int T = out_size / BS;
    for (int t = 0; t < T; ++t) {
        const int p = t & 1;
        k_gates<<<256, 256, 0, stream>>>(xb,
                                         hfp[p], hfp[p ^ 1], cf, Wih_f, Whh_f, b_f,
                                         hbp[p], hbp[p ^ 1], cb, Wih_b, Whh_b, b_b);
        k_next<<<16 + BS, 256, 0, stream>>>(hfp[p ^ 1], hbp[p ^ 1],
                                            W_out, b_out, W_fc1, b_fc1,
                                            xb, out, T, t);
    }
}

// Round 2
// 33131.949 us; speedup vs baseline: 2.1739x; 2.1739x over previous
//
#include <hip/hip_runtime.h>
#include <math.h>

#define BS   128
#define LAT  512
#define HID  1024

typedef unsigned short u16;
typedef __attribute__((ext_vector_type(8))) short short8;
typedef __attribute__((ext_vector_type(4))) float f32x4;
typedef __attribute__((ext_vector_type(4))) unsigned short u16x4;

__device__ __forceinline__ float sigm(float x) { return 1.0f / (1.0f + expf(-x)); }

// round-to-nearest-even float -> bf16 (as u16)
__device__ __forceinline__ u16 f2bf(float x) {
    union { float f; unsigned u; } v; v.f = x;
    unsigned r = v.u + 0x7fffu + ((v.u >> 16) & 1u);
    return (u16)(r >> 16);
}
__device__ __forceinline__ float bf2f(u16 h) {
    union { unsigned u; float f; } v; v.u = ((unsigned)h) << 16;
    return v.f;
}

__device__ __forceinline__ f32x4 mfma16(short8 a, short8 b, f32x4 c) {
    return __builtin_amdgcn_mfma_f32_16x16x32_bf16(a, b, c, 0, 0, 0);
}

// async global->LDS, 16B per lane; lds dest = base + lane*16 (wave-uniform base)
__device__ __forceinline__ void gl_lds16(const void* g, void* l) {
    __builtin_amdgcn_global_load_lds(
        (const __attribute__((address_space(1))) unsigned int*)g,
        (__attribute__((address_space(3))) unsigned int*)l, 16, 0, 0);
}

// XOR swizzle for LDS W tiles (row stride 64B): slot(q,n) = q ^ f(n)
__device__ __forceinline__ int swz(int n) { return (n ^ (n >> 2)) & 3; }

// ---------------------------------------------------------------------------
// K1: gates. 256 blocks x 256 thr. Block = (dir, 32 z-cols), M=128, K=1536.
// z-col layout: col' = dir*4096 + u*4 + g  (g in {i,f,g,o}).
// Wave w: m in [32w, 32w+32), wave-tile 32x32, mfma 16x16x32 bf16, 3-product.
// W staged in LDS (double buf) via global_load_lds; A frags direct from global.
// Epilogue: z -> LDS transpose -> gates -> c (fp32, in place), h -> bf16 hi/lo
// into next A planes (h region = cols [512,1536)).
// ---------------------------------------------------------------------------
__global__ __launch_bounds__(256) void k_gates(
    const u16* __restrict__ Afh, const u16* __restrict__ Afl,
    const u16* __restrict__ Abh, const u16* __restrict__ Abl,
    u16* __restrict__ Nfh, u16* __restrict__ Nfl,
    u16* __restrict__ Nbh, u16* __restrict__ Nbl,
    const u16* __restrict__ WH, const u16* __restrict__ WL,
    const float* __restrict__ BR, float* __restrict__ CF, float* __restrict__ CB)
{
    __shared__ __align__(16) char sm[4 * 4608];   // loop: [0,8192) = 2 W bufs; epi: 4x(32x36 f32)

    const int tid = threadIdx.x;
    const int bid = blockIdx.x;
    const int dir = bid >> 7;
    const int n0g = bid * 32;
    const int w = tid >> 6, lane = tid & 63, l15 = lane & 15, quad = lane >> 4;

    const u16* Ah = dir ? Abh : Afh;
    const u16* Al = dir ? Abl : Afl;

    // staging role of this wave: plane = w>>1 (0 hi,1 lo), rows half = w&1
    const int half = w & 1;
    const int sn = half * 16 + (lane >> 2);
    const int qg = (lane & 3) ^ swz(sn);
    const u16* wsrc = ((w >> 1) ? WL : WH) + (size_t)(n0g + sn) * 1536 + qg * 8;
    const int smoff_w = (w >> 1) * 2048 + half * 1024;

    // A fragment addresses (k added per chunk)
    const size_t arow0 = (size_t)(w * 32 + l15) * 1536 + quad * 8;
    const size_t arow1 = arow0 + 16 * 1536;

    // b-frag LDS offsets (within one buf)
    int boff[2][2];
#pragma unroll
    for (int pl = 0; pl < 2; ++pl)
#pragma unroll
        for (int nt = 0; nt < 2; ++nt) {
            const int bn = nt * 16 + l15;
            boff[pl][nt] = pl * 2048 + bn * 64 + (quad ^ swz(bn)) * 16;
        }

    f32x4 acc[2][2] = {};
    short8 ah[2][2], al_[2][2];

    // prologue: stage chunk0 -> buf0, prefetch A chunk0 -> set0
    gl_lds16(wsrc, sm + smoff_w);
    ah[0][0]  = *(const short8*)(Ah + arow0);
    ah[0][1]  = *(const short8*)(Ah + arow1);
    al_[0][0] = *(const short8*)(Al + arow0);
    al_[0][1] = *(const short8*)(Al + arow1);

#pragma unroll 2
    for (int c = 0; c < 48; ++c) {
        __syncthreads();                       // stage(c)+prefetch(c) drained here
        const int cur = c & 1, nxt = cur ^ 1;
        if (c + 1 < 48) {
            const int k1 = (c + 1) * 32;
            gl_lds16(wsrc + k1, sm + nxt * 4096 + smoff_w);
            ah[nxt][0]  = *(const short8*)(Ah + arow0 + k1);
            ah[nxt][1]  = *(const short8*)(Ah + arow1 + k1);
            al_[nxt][0] = *(const short8*)(Al + arow0 + k1);
            al_[nxt][1] = *(const short8*)(Al + arow1 + k1);
        }
        const char* bb = sm + cur * 4096;
        const short8 bh0 = *(const short8*)(bb + boff[0][0]);
        const short8 bh1 = *(const short8*)(bb + boff[0][1]);
        const short8 bl0 = *(const short8*)(bb + boff[1][0]);
        const short8 bl1 = *(const short8*)(bb + boff[1][1]);
        const short8 a0 = ah[cur][0], a1 = ah[cur][1];
        const short8 q0 = al_[cur][0], q1 = al_[cur][1];
        acc[0][0] = mfma16(a0, bh0, acc[0][0]);
        acc[1][0] = mfma16(a1, bh0, acc[1][0]);
        acc[0][1] = mfma16(a0, bh1, acc[0][1]);
        acc[1][1] = mfma16(a1, bh1, acc[1][1]);
        acc[0][0] = mfma16(a0, bl0, acc[0][0]);
        acc[1][0] = mfma16(a1, bl0, acc[1][0]);
        acc[0][1] = mfma16(a0, bl1, acc[0][1]);
        acc[1][1] = mfma16(a1, bl1, acc[1][1]);
        acc[0][0] = mfma16(q0, bh0, acc[0][0]);
        acc[1][0] = mfma16(q1, bh0, acc[1][0]);
        acc[0][1] = mfma16(q0, bh1, acc[0][1]);
        acc[1][1] = mfma16(q1, bh1, acc[1][1]);
    }

    __syncthreads();    // everyone done with staging bufs before epi overwrite

    // z tile -> LDS (per-wave private region, stride 36 floats)
    char* zb = sm + w * 4608;
#pragma unroll
    for (int mt = 0; mt < 2; ++mt)
#pragma unroll
        for (int nt = 0; nt < 2; ++nt)
#pragma unroll
            for (int r = 0; r < 4; ++r) {
                const int mrow = mt * 16 + quad * 4 + r;
                const int col = nt * 16 + l15;
                *(float*)(zb + mrow * 144 + col * 4) = acc[mt][nt][r];
            }

    float* cst = dir ? CB : CF;
    u16* Nh = dir ? Nbh : Nfh;
    u16* Nl = dir ? Nbl : Nfl;
    const int ubase = (bid & 127) * 8;
#pragma unroll
    for (int p2 = 0; p2 < 4; ++p2) {
        const int idx = lane + 64 * p2;   // 256 (m,u) pairs per wave
        const int ml = idx >> 3;
        const int u8 = idx & 7;
        const f32x4 z = *(const f32x4*)(zb + ml * 144 + u8 * 16);
        const f32x4 bz = *(const f32x4*)(BR + n0g + u8 * 4);
        const float zi = z[0] + bz[0], zf = z[1] + bz[1];
        const float zg = z[2] + bz[2], zo = z[3] + bz[3];
        const int m = w * 32 + ml;
        const int u = ubase + u8;
        const size_t cidx = (size_t)m * 1024 + u;
        const float cold = cst[cidx];
        const float c2 = sigm(zf) * cold + sigm(zi) * tanhf(zg);
        const float h2 = sigm(zo) * tanhf(c2);
        cst[cidx] = c2;
        const size_t hidx = (size_t)m * 1536 + 512 + u;
        const u16 hh = f2bf(h2);
        Nh[hidx] = hh;
        Nl[hidx] = f2bf(h2 - bf2f(hh));
    }
}

// ---------------------------------------------------------------------------
// K2: blocks 0..31: x_next = hb @ W_out^T + b_out (M=128, N-tile 16, K=1024),
//     written as bf16 hi/lo into x region (cols [0,512)) of BOTH next planes.
//     blocks 32..159: out[b,t] = relu([hf|hb]) . W_fc1 + b_fc1.
// ---------------------------------------------------------------------------
__global__ __launch_bounds__(256) void k_next(
    u16* __restrict__ Nfh, u16* __restrict__ Nfl,
    u16* __restrict__ Nbh, u16* __restrict__ Nbl,
    const u16* __restrict__ WOH, const u16* __restrict__ WOL,
    const float* __restrict__ b_out, const float* __restrict__ W_fc1,
    const float* __restrict__ b_fc1, float* __restrict__ out, int T, int t)
{
    __shared__ __align__(16) char sm[4096];
    __shared__ float red[256];
    const int tid = threadIdx.x;
    const int bid = blockIdx.x;
    const int w = tid >> 6, lane = tid & 63, l15 = lane & 15, quad = lane >> 4;

    if (bid < 32) {
        const int n0 = bid * 16;
        // staging: wave0 = hi plane, wave1 = lo plane
        const int sn = lane >> 2;
        const int qg = (lane & 3) ^ swz(sn);
        const u16* wsrc = (w ? WOL : WOH) + (size_t)(n0 + sn) * 1024 + qg * 8;

        const size_t arow0 = (size_t)(w * 32 + l15) * 1536 + 512 + quad * 8;
        const size_t arow1 = arow0 + 16 * 1536;

        const int boffH = l15 * 64 + (quad ^ swz(l15)) * 16;
        const int boffL = 1024 + boffH;

        f32x4 acc2[2] = {};
        short8 ah[2][2], al_[2][2];
        if (w < 2) gl_lds16(wsrc, sm + w * 1024);
        ah[0][0]  = *(const short8*)(Nbh + arow0);
        ah[0][1]  = *(const short8*)(Nbh + arow1);
        al_[0][0] = *(const short8*)(Nbl + arow0);
        al_[0][1] = *(const short8*)(Nbl + arow1);

#pragma unroll 2
        for (int c = 0; c < 32; ++c) {
            __syncthreads();
            const int cur = c & 1, nxt = cur ^ 1;
            if (c + 1 < 32) {
                const int k1 = (c + 1) * 32;
                if (w < 2) gl_lds16(wsrc + k1, sm + nxt * 2048 + w * 1024);
                ah[nxt][0]  = *(const short8*)(Nbh + arow0 + k1);
                ah[nxt][1]  = *(const short8*)(Nbh + arow1 + k1);
                al_[nxt][0] = *(const short8*)(Nbl + arow0 + k1);
                al_[nxt][1] = *(const short8*)(Nbl + arow1 + k1);
            }
            const char* bb = sm + cur * 2048;
            const short8 bh = *(const short8*)(bb + boffH);
            const short8 bl = *(const short8*)(bb + boffL);
            acc2[0] = mfma16(ah[cur][0], bh, acc2[0]);
            acc2[1] = mfma16(ah[cur][1], bh, acc2[1]);
            acc2[0] = mfma16(ah[cur][0], bl, acc2[0]);
            acc2[1] = mfma16(ah[cur][1], bl, acc2[1]);
            acc2[0] = mfma16(al_[cur][0], bh, acc2[0]);
            acc2[1] = mfma16(al_[cur][1], bh, acc2[1]);
        }

        const int col = n0 + l15;
        const float bo = b_out[col];
#pragma unroll
        for (int mt = 0; mt < 2; ++mt)
#pragma unroll
            for (int r = 0; r < 4; ++r) {
                const int m = w * 32 + mt * 16 + quad * 4 + r;
                const float xv = acc2[mt][r] + bo;
                const u16 hh = f2bf(xv);
                const u16 ll = f2bf(xv - bf2f(hh));
                const size_t idx = (size_t)m * 1536 + col;
                Nfh[idx] = hh; Nfl[idx] = ll;
                Nbh[idx] = hh; Nbl[idx] = ll;
            }
    } else {
        const int b = bid - 32;
        const size_t base = (size_t)b * 1536 + 512;
        const int j0 = tid * 4;
        const u16x4 fh = *(const u16x4*)(Nfh + base + j0);
        const u16x4 fl = *(const u16x4*)(Nfl + base + j0);
        const u16x4 bh4 = *(const u16x4*)(Nbh + base + j0);
        const u16x4 bl4 = *(const u16x4*)(Nbl + base + j0);
        const f32x4 wf = *(const f32x4*)(W_fc1 + j0);
        const f32x4 wb = *(const f32x4*)(W_fc1 + 1024 + j0);
        float s = 0.0f;
#pragma unroll
        for (int k = 0; k < 4; ++k) {
            const float hf = fmaxf(bf2f(fh[k]) + bf2f(fl[k]), 0.0f);
            const float hb = fmaxf(bf2f(bh4[k]) + bf2f(bl4[k]), 0.0f);
            s = fmaf(hf, wf[k], s);
            s = fmaf(hb, wb[k], s);
        }
        red[tid] = s;
        __syncthreads();
        for (int off = 128; off > 0; off >>= 1) {
            if (tid < off) red[tid] += red[tid + off];
            __syncthreads();
        }
        if (tid == 0) out[(size_t)b * T + t] = red[0] + b_fc1[0];
    }
}

// ---------------------------------------------------------------------------
// Prep: W (gate-interleaved cols, concat [Wih|Whh] along K) -> hi/lo bf16.
// ---------------------------------------------------------------------------
__global__ __launch_bounds__(256) void k_prep_w(
    const float* __restrict__ Wih_f, const float* __restrict__ Whh_f,
    const float* __restrict__ Wih_b, const float* __restrict__ Whh_b,
    u16* __restrict__ WH, u16* __restrict__ WL)
{
    const int t = blockIdx.x * 256 + threadIdx.x;   // < 1,572,864
    const int col = t / 192;
    const int kb = (t % 192) * 8;
    const int dirb = col >> 12;
    const int rem = col & 4095;
    const int u = rem >> 2, g = rem & 3;
    const int srow = g * 1024 + u;
    const float* Wih = dirb ? Wih_b : Wih_f;
    const float* Whh = dirb ? Whh_b : Whh_f;
    const float* src = (kb < 512) ? (Wih + (size_t)srow * 512 + kb)
                                  : (Whh + (size_t)srow * 1024 + (kb - 512));
    const size_t dst = (size_t)col * 1536 + kb;
#pragma unroll
    for (int j = 0; j < 8; ++j) {
        const float v = src[j];
        const u16 hh = f2bf(v);
        WH[dst + j] = hh;
        WL[dst + j] = f2bf(v - bf2f(hh));
    }
}

// Wout hi/lo, reordered bias, A0 (x = decoder_input, h = 0)
__global__ __launch_bounds__(256) void k_prep_misc(
    const float* __restrict__ W_out, const float* __restrict__ b_f,
    const float* __restrict__ b_b, const float* __restrict__ dec,
    u16* __restrict__ WOH, u16* __restrict__ WOL, float* __restrict__ BR,
    u16* __restrict__ A0fh, u16* __restrict__ A0fl,
    u16* __restrict__ A0bh, u16* __restrict__ A0bl)
{
    const int t = blockIdx.x * 256 + threadIdx.x;   // < 98,304
    if (t < 65536) {
        const int n = t >> 7;
        const int kb = (t & 127) * 8;
        const size_t s0 = (size_t)n * 1024 + kb;
#pragma unroll
        for (int j = 0; j < 8; ++j) {
            const float v = W_out[s0 + j];
            const u16 hh = f2bf(v);
            WOH[s0 + j] = hh;
            WOL[s0 + j] = f2bf(v - bf2f(hh));
        }
    } else if (t < 73728) {
        const int col = t - 65536;
        const int dirb = col >> 12;
        const int rem = col & 4095;
        BR[col] = (dirb ? b_b : b_f)[(rem & 3) * 1024 + (rem >> 2)];
    } else {
        const int i = t - 73728;                    // < 24576
        const int m = i / 192;
        const int kb = (i % 192) * 8;
#pragma unroll
        for (int j = 0; j < 8; ++j) {
            const int k = kb + j;
            const float v = (k < 512) ? dec[(size_t)m * 512 + k] : 0.0f;
            const u16 hh = f2bf(v);
            const u16 ll = f2bf(v - bf2f(hh));
            const size_t idx = (size_t)m * 1536 + k;
            A0fh[idx] = hh; A0fl[idx] = ll;
            A0bh[idx] = hh; A0bl[idx] = ll;
        }
    }
}

// ---------------------------------------------------------------------------
// ws layout (bytes):
//  0          WH   25,165,824      (8192 x 1536 bf16)
//  25165824   WL   25,165,824
//  50331648   WOH   1,048,576      (512 x 1024 bf16)
//  51380224   WOL   1,048,576
//  52428800   A planes, 8 x 393,216: [Afh0 Afl0 Abh0 Abl0 Afh1 Afl1 Abh1 Abl1]
//  55574528   CF    524,288  (fp32, zeroed)
//  56098816   CB    524,288  (fp32, zeroed)
//  56623104   BR     32,768  (fp32)
// ---------------------------------------------------------------------------
extern "C" void kernel_launch(void* const* d_in, const int* in_sizes, int n_in,
                              void* d_out, int out_size, void* d_ws, size_t ws_size,
                              hipStream_t stream) {
    const float* dec   = (const float*)d_in[0];
    const float* Wih_f = (const float*)d_in[2];
    const float* Whh_f = (const float*)d_in[3];
    const float* b_f   = (const float*)d_in[4];
    const float* Wih_b = (const float*)d_in[5];
    const float* Whh_b = (const float*)d_in[6];
    const float* b_b   = (const float*)d_in[7];
    const float* W_out = (const float*)d_in[8];
    const float* b_out = (const float*)d_in[9];
    const float* W_fc1 = (const float*)d_in[10];
    const float* b_fc1 = (const float*)d_in[11];
    float* out = (float*)d_out;

    char* ws = (char*)d_ws;
    u16* WH  = (u16*)(ws);
    u16* WL  = (u16*)(ws + 25165824);
    u16* WOH = (u16*)(ws + 50331648);
    u16* WOL = (u16*)(ws + 51380224);
    u16* Ap[8];
    for (int i = 0; i < 8; ++i) Ap[i] = (u16*)(ws + 52428800 + (size_t)i * 393216);
    float* CF = (float*)(ws + 55574528);
    float* CB = (float*)(ws + 56098816);
    float* BR = (float*)(ws + 56623104);

    k_prep_w<<<6144, 256, 0, stream>>>(Wih_f, Whh_f, Wih_b, Whh_b, WH, WL);
    k_prep_misc<<<384, 256, 0, stream>>>(W_out, b_f, b_b, dec, WOH, WOL, BR,
                                         Ap[0], Ap[1], Ap[2], Ap[3]);
    hipMemsetAsync(CF, 0, 1048576, stream);   // CF+CB contiguous

    const int T = out_size / BS;
    for (int t = 0; t < T; ++t) {
        const int p = (t & 1) * 4;
        const int q = 4 - p;
        k_gates<<<256, 256, 0, stream>>>(Ap[p], Ap[p + 1], Ap[p + 2], Ap[p + 3],
                                         Ap[q], Ap[q + 1], Ap[q + 2], Ap[q + 3],
                                         WH, WL, BR, CF, CB);
        k_next<<<160, 256, 0, stream>>>(Ap[q], Ap[q + 1], Ap[q + 2], Ap[q + 3],
                                        WOH, WOL, b_out, W_fc1, b_fc1, out, T, t);
    }
}